// Round 8
// baseline (208.964 us; speedup 1.0000x reference)
//
#include <hip/hip_runtime.h>
#include <hip/hip_cooperative_groups.h>
#include <math.h>

namespace cg = cooperative_groups;

#define BSZ   256
#define RANK  16
#define IN_D  784
#define H1D   512
#define OUT_D 10
#define TOTAL 29610
#define GSTRIDE 29616   // padded g row stride (16B-aligned rows)
#define LDB 132         // LDS B row stride (shorts)
#define NTILES 232      // ceil(TOTAL/128)

// g layout offsets (per batch row)
#define OFF_A1    0
#define OFF_B1F   8192
#define OFF_BIAS1 20736
#define OFF_A2    21248
#define OFF_B2F   21408
#define OFF_BIAS2 29600

typedef __attribute__((ext_vector_type(8))) short short8;
typedef __attribute__((ext_vector_type(4))) short short4v;
typedef __attribute__((ext_vector_type(4))) float f32x4;

__device__ __forceinline__ short f2bf(float f) {      // RNE fp32 -> bf16
    unsigned u = __float_as_uint(f);
    unsigned r = (u + 0x7fffu + ((u >> 16) & 1u)) >> 16;
    return (short)r;
}
__device__ __forceinline__ float bf2f(short s) {
    return __uint_as_float(((unsigned)(unsigned short)s) << 16);
}

// ---------------- cooperative mega-kernel: front_style | gemm | apply ----------------
// 256 blocks x 512 threads, 1 block/CU. Phases separated by grid.sync().
__global__ __launch_bounds__(512, 1) void mega_k(
    const float* __restrict__ img,
    const float* __restrict__ c1w, const float* __restrict__ c1b,
    const float* __restrict__ c2w, const float* __restrict__ c2b,
    const float* __restrict__ sew, const float* __restrict__ seb,
    const float* __restrict__ g1w, const float* __restrict__ g1b,
    const float* __restrict__ g2w, const float* __restrict__ g2b,
    short* __restrict__ Shi, short* __restrict__ Slo,
    float* __restrict__ g, float* __restrict__ out) {
    __shared__ char smem[67584] __attribute__((aligned(16)));   // max of all phases
    cg::grid_group grid = cg::this_grid();
    int b = blockIdx.x, tid = threadIdx.x;

    // ================= Phase A: conv1+conv2+style+g1 (batch = blockIdx) =================
    {
        float* xs    = (float*)smem;          // 784
        float* w1s   = xs + 784;              // 144
        float* b1s   = w1s + 144;             // 16
        float* b2s   = b1s + 16;              // 32
        float* h1p   = b2s + 32;              // 3584  [ic][iy][16]
        float* c2ws  = h1p + 3584;            // 4608  native [oc][ic*9+t]
        float* h2l   = c2ws + 4608;           // 1568
        float* red   = h2l + 1568;            // 512
        float* style = red + 512;             // 64    (total 11332 floats = 45.3 KB)
        if (tid < 196) ((float4*)xs)[tid] = ((const float4*)(img + b * 784))[tid];
        if (tid < 144) w1s[tid] = c1w[tid];
        for (int i = tid; i < 1152; i += 512) ((float4*)c2ws)[i] = ((const float4*)c2w)[i];
        if (tid < 16) b1s[tid] = c1b[tid];
        if (tid < 32) b2s[tid] = c2b[tid];
        __syncthreads();
        // conv1: 16 oc x 14x14, stride 2 pad 1
#pragma unroll 1
        for (int o = tid; o < 3136; o += 512) {
            int oc = o / 196, pos = o % 196, oy = pos / 14, ox = pos % 14;
            float acc = b1s[oc];
            const float* wb = &w1s[oc * 9];
#pragma unroll
            for (int ky = 0; ky < 3; ky++) {
                int iy = oy * 2 - 1 + ky;
                if ((unsigned)iy < 28u) {
#pragma unroll
                    for (int kx = 0; kx < 3; kx++) {
                        int ix = ox * 2 - 1 + kx;
                        if ((unsigned)ix < 28u) acc += xs[iy * 28 + ix] * wb[ky * 3 + kx];
                    }
                }
            }
            h1p[oc * 224 + oy * 16 + ox] = fmaxf(acc, 0.f);
        }
        __syncthreads();
        // conv2: 32 oc x 7x7 -> h2l (tid<224 active: oc=tid&31, oy=tid>>5)
        {
            int oc = tid & 31, oy = tid >> 5;
            if (oy < 7) {
                float a7[7];
#pragma unroll
                for (int ox = 0; ox < 7; ox++) a7[ox] = b2s[oc];
#pragma unroll 1
                for (int ic = 0; ic < 16; ic++) {
                    const float* wp = &c2ws[oc * 144 + ic * 9];
                    float w[9];
#pragma unroll
                    for (int t = 0; t < 9; t++) w[t] = wp[t];
#pragma unroll
                    for (int ky = 0; ky < 3; ky++) {
                        int iy = oy * 2 - 1 + ky;
                        if ((unsigned)iy < 14u) {
                            const float4* rp = (const float4*)&h1p[ic * 224 + iy * 16];
                            float r[16];
#pragma unroll
                            for (int q = 0; q < 4; q++) {
                                float4 v = rp[q];
                                r[q * 4 + 0] = v.x; r[q * 4 + 1] = v.y;
                                r[q * 4 + 2] = v.z; r[q * 4 + 3] = v.w;
                            }
#pragma unroll
                            for (int ox = 0; ox < 7; ox++) {
#pragma unroll
                                for (int kx = 0; kx < 3; kx++) {
                                    int ix = 2 * ox + kx - 1;
                                    if (ix >= 0) a7[ox] += r[ix] * w[ky * 3 + kx];
                                }
                            }
                        }
                    }
                }
                float* dst = h2l + oc * 49 + oy * 7;
#pragma unroll
                for (int ox = 0; ox < 7; ox++) dst[ox] = fmaxf(a7[ox], 0.f);
            }
        }
        __syncthreads();
        // style = tanh(h2 @ sew.T + seb): 64 outputs x 8 K-partials (49 float4 each), 7-ILP
        {
            int j = tid & 63, p = tid >> 6;
            const float4* wr = (const float4*)(sew + j * 1568) + p * 49;
            const float4* hr = (const float4*)h2l + p * 49;
            float a[7] = {0.f, 0.f, 0.f, 0.f, 0.f, 0.f, 0.f};
#pragma unroll 1
            for (int i = 0; i < 49; i += 7) {
#pragma unroll
                for (int u = 0; u < 7; u++) {
                    float4 w = wr[i + u], h = hr[i + u];
                    a[u] += w.x * h.x + w.y * h.y + w.z * h.z + w.w * h.w;
                }
            }
            red[p * 64 + j] = ((a[0] + a[1]) + (a[2] + a[3])) + ((a[4] + a[5]) + a[6]);
        }
        __syncthreads();
        if (tid < 64) {
            float a = seb[tid];
#pragma unroll
            for (int p = 0; p < 8; p++) a += red[p * 64 + tid];
            style[tid] = tanhf(a);
        }
        __syncthreads();
        // s128 = relu(style @ g1w.T + g1b) -> bf16 hi/lo split
        if (tid < 128) {
            const float4* wr = (const float4*)(g1w + tid * 64);
            const float4* sv = (const float4*)style;
            float acc = g1b[tid];
#pragma unroll
            for (int q = 0; q < 16; q++) {
                float4 w = wr[q], s = sv[q];
                acc += w.x * s.x + w.y * s.y + w.z * s.z + w.w * s.w;
            }
            float v = fmaxf(acc, 0.f);
            short hi = f2bf(v);
            Shi[b * 128 + tid] = hi;
            Slo[b * 128 + tid] = f2bf(v - bf2f(hi));
        }
    }

    grid.sync();

    // ================= Phase B: g = S.W^T + g2b (n-tile = blockIdx, 232 tiles) =================
    if (b < NTILES) {
        short* Bhi = (short*)smem;            // 128*132 shorts
        short* Blo = Bhi + 128 * LDB;         // total 67584 B exact
        int n0 = b * 128;
        // stage + split B tile: 4 threads per row, 32 floats each
        {
            int r = tid >> 2, h = tid & 3;
            int t = n0 + r;
            short* dhi = Bhi + r * LDB + h * 32;
            short* dlo = Blo + r * LDB + h * 32;
            if (t < TOTAL) {
                const float4* src = (const float4*)(g2w + (long)t * 128 + h * 32);
#pragma unroll
                for (int i = 0; i < 8; i++) {
                    float4 wv = src[i];
                    short4v ph, pl;
                    ph.x = f2bf(wv.x); ph.y = f2bf(wv.y); ph.z = f2bf(wv.z); ph.w = f2bf(wv.w);
                    pl.x = f2bf(wv.x - bf2f(ph.x)); pl.y = f2bf(wv.y - bf2f(ph.y));
                    pl.z = f2bf(wv.z - bf2f(ph.z)); pl.w = f2bf(wv.w - bf2f(ph.w));
                    *(short4v*)(dhi + i * 4) = ph;
                    *(short4v*)(dlo + i * 4) = pl;
                }
            } else {
                short4v z = {0, 0, 0, 0};
#pragma unroll
                for (int i = 0; i < 8; i++) { *(short4v*)(dhi + i * 4) = z; *(short4v*)(dlo + i * 4) = z; }
            }
        }
        __syncthreads();
        int lane = tid & 63, w = tid >> 6;
        int col = lane & 15, quad = lane >> 4;
        short8 Ah[2][4], Al[2][4];
#pragma unroll
        for (int mt = 0; mt < 2; mt++) {
            int mrow = w * 32 + mt * 16 + col;
#pragma unroll
            for (int ks = 0; ks < 4; ks++) {
                Ah[mt][ks] = *(const short8*)(Shi + mrow * 128 + ks * 32 + quad * 8);
                Al[mt][ks] = *(const short8*)(Slo + mrow * 128 + ks * 32 + quad * 8);
            }
        }
        f32x4 acc[2][8];
#pragma unroll
        for (int mt = 0; mt < 2; mt++)
#pragma unroll
            for (int nt = 0; nt < 8; nt++) acc[mt][nt] = (f32x4){0.f, 0.f, 0.f, 0.f};
#pragma unroll
        for (int nt = 0; nt < 8; nt++) {
#pragma unroll
            for (int ks = 0; ks < 4; ks++) {
                int bofs = (nt * 16 + col) * LDB + ks * 32 + quad * 8;
                short8 bh = *(const short8*)(Bhi + bofs);
                short8 bl = *(const short8*)(Blo + bofs);
#pragma unroll
                for (int mt = 0; mt < 2; mt++) {
                    acc[mt][nt] = __builtin_amdgcn_mfma_f32_16x16x32_bf16(Ah[mt][ks], bh, acc[mt][nt], 0, 0, 0);
                    acc[mt][nt] = __builtin_amdgcn_mfma_f32_16x16x32_bf16(Al[mt][ks], bh, acc[mt][nt], 0, 0, 0);
                    acc[mt][nt] = __builtin_amdgcn_mfma_f32_16x16x32_bf16(Ah[mt][ks], bl, acc[mt][nt], 0, 0, 0);
                }
            }
        }
        // epilogue: C col = lane&15 (t), row = quad*4 + j (batch)
#pragma unroll
        for (int nt = 0; nt < 8; nt++) {
            int tcol = n0 + nt * 16 + col;
            if (tcol < TOTAL) {
                float bias = g2b[tcol];
#pragma unroll
                for (int mt = 0; mt < 2; mt++) {
                    int rbase = w * 32 + mt * 16 + quad * 4;
#pragma unroll
                    for (int j = 0; j < 4; j++)
                        g[(long)(rbase + j) * GSTRIDE + tcol] = acc[mt][nt][j] + bias;
                }
            }
        }
    }

    grid.sync();

    // ================= Phase C: low-rank apply (batch = blockIdx) =================
    {
        float* x   = (float*)smem;            // 784
        float* red = x + 784;                 // 512
        float* v1  = red + 512;               // 16
        float* h1s = v1 + 16;                 // 512
        float* v2  = h1s + 512;               // 16
        const float* gb = g + (long)b * GSTRIDE;
        if (tid < 196) ((float4*)x)[tid] = ((const float4*)(img + b * IN_D))[tid];
        __syncthreads();
        // v1[r] = B1F[r,:].x  (7 loads in flight)
        {
            int r = tid >> 5, p = tid & 31;
            const float4* row = (const float4*)(gb + OFF_B1F + r * IN_D);
            const float4* x4 = (const float4*)x;
            float a[7] = {0.f, 0.f, 0.f, 0.f, 0.f, 0.f, 0.f};
#pragma unroll
            for (int u = 0; u < 7; u++) {
                int i = p + u * 32;
                if (i < 196) {
                    float4 w = row[i], xv = x4[i];
                    a[u] += w.x * xv.x + w.y * xv.y + w.z * xv.z + w.w * xv.w;
                }
            }
            red[tid] = ((a[0] + a[1]) + (a[2] + a[3])) + ((a[4] + a[5]) + a[6]);
        }
        __syncthreads();
        if (tid < 16) {
            float s = 0.f;
#pragma unroll
            for (int p = 0; p < 32; p++) s += red[tid * 32 + p];
            v1[tid] = s;
        }
        __syncthreads();
        {
            const float4* row = (const float4*)(gb + OFF_A1 + tid * RANK);
            float acc = gb[OFF_BIAS1 + tid];
            const float4* v14 = (const float4*)v1;
#pragma unroll
            for (int q = 0; q < 4; q++) {
                float4 a = row[q], v = v14[q];
                acc += a.x * v.x + a.y * v.y + a.z * v.z + a.w * v.w;
            }
            h1s[tid] = fmaxf(acc, 0.f);
        }
        __syncthreads();
        // v2[r] = B2F[r,:].h1 (4 loads in flight)
        {
            int r = tid >> 5, p = tid & 31;
            const float4* row = (const float4*)(gb + OFF_B2F + r * H1D);
            const float4* h4 = (const float4*)h1s;
            float a[4] = {0.f, 0.f, 0.f, 0.f};
#pragma unroll
            for (int u = 0; u < 4; u++) {
                int i = p + u * 32;
                float4 w = row[i], hv = h4[i];
                a[u] += w.x * hv.x + w.y * hv.y + w.z * hv.z + w.w * hv.w;
            }
            red[tid] = (a[0] + a[1]) + (a[2] + a[3]);
        }
        __syncthreads();
        if (tid < 16) {
            float s = 0.f;
#pragma unroll
            for (int p = 0; p < 32; p++) s += red[tid * 32 + p];
            v2[tid] = s;
        }
        __syncthreads();
        if (tid < OUT_D) {
            const float* row = gb + OFF_A2 + tid * RANK;
            float acc = gb[OFF_BIAS2 + tid];
#pragma unroll
            for (int r = 0; r < RANK; r++) acc += row[r] * v2[r];
            out[b * OUT_D + tid] = acc;
        }
    }
}

extern "C" void kernel_launch(void* const* d_in, const int* in_sizes, int n_in,
                              void* d_out, int out_size, void* d_ws, size_t ws_size,
                              hipStream_t stream) {
    const float* images = (const float*)d_in[0];
    const float* c1w = (const float*)d_in[1];
    const float* c1b = (const float*)d_in[2];
    const float* c2w = (const float*)d_in[3];
    const float* c2b = (const float*)d_in[4];
    const float* sew = (const float*)d_in[5];
    const float* seb = (const float*)d_in[6];
    const float* g1w = (const float*)d_in[7];
    const float* g1b = (const float*)d_in[8];
    const float* g2w = (const float*)d_in[9];
    const float* g2b = (const float*)d_in[10];
    float* out = (float*)d_out;

    float* ws = (float*)d_ws;
    short* Shi = (short*)ws;                 // 32768 shorts
    short* Slo = Shi + 32768;                // 32768 shorts
    float* g   = ws + 32768;                 // 256*29616 floats (~30.3 MB)

    void* args[] = {
        (void*)&images, (void*)&c1w, (void*)&c1b, (void*)&c2w, (void*)&c2b,
        (void*)&sew, (void*)&seb, (void*)&g1w, (void*)&g1b, (void*)&g2w, (void*)&g2b,
        (void*)&Shi, (void*)&Slo, (void*)&g, (void*)&out
    };
    hipLaunchCooperativeKernel((const void*)mega_k, dim3(BSZ), dim3(512), args, 0, stream);
}

// Round 9
// 126.879 us; speedup vs baseline: 1.6470x; 1.6470x over previous
//
#include <hip/hip_runtime.h>
#include <math.h>

#define BSZ   256
#define RANK  16
#define IN_D  784
#define H1D   512
#define OUT_D 10
#define TOTAL 29610
#define GSTRIDE 29616   // padded g row stride (16B-aligned rows)
#define LDB 132         // LDS B row stride (shorts)
#define C2LD 145        // conv2 weight LDS row stride (odd -> bank-conflict-free oc reads)

// g layout offsets (per batch row)
#define OFF_A1    0
#define OFF_B1F   8192
#define OFF_BIAS1 20736
#define OFF_A2    21248
#define OFF_B2F   21408
#define OFF_BIAS2 29600

typedef __attribute__((ext_vector_type(8))) short short8;
typedef __attribute__((ext_vector_type(4))) short short4v;
typedef __attribute__((ext_vector_type(4))) float f32x4;

__device__ __forceinline__ short f2bf(float f) {      // RNE fp32 -> bf16
    unsigned u = __float_as_uint(f);
    unsigned r = (u + 0x7fffu + ((u >> 16) & 1u)) >> 16;
    return (short)r;
}
__device__ __forceinline__ float bf2f(short s) {
    return __uint_as_float(((unsigned)(unsigned short)s) << 16);
}

// ---------------- prep: sewTv[g*256 + j*4 + c] = sew[j*1568 + g*4 + c] ----------------
// (g = i>>2, c = i&3). style then loads float4 at (g*64 + j) with lane-consecutive j
// -> 64 lanes x 16B contiguous = fully-coalesced 1KB per instruction.
__global__ __launch_bounds__(256) void prep_k(const float* __restrict__ sew,
                                              float* __restrict__ sewTv) {
    int idx = blockIdx.x * 256 + threadIdx.x;   // 392 blocks x 256 = 100352 exactly
    int g = idx >> 8, r = idx & 255;
    int j = r >> 2, c = r & 3;
    sewTv[idx] = sew[j * 1568 + g * 4 + c];
}

// ---------------- fused conv1+conv2+style per batch: img -> Shi/Slo ----------------
__global__ __launch_bounds__(256) void front_style_k(
    const float* __restrict__ img, const float* __restrict__ c1w, const float* __restrict__ c1b,
    const float* __restrict__ c2w, const float* __restrict__ c2b,
    const float* __restrict__ sewTv, const float* __restrict__ seb,
    const float* __restrict__ g1w, const float* __restrict__ g1b,
    short* __restrict__ Shi, short* __restrict__ Slo) {
    __shared__ float xs[784];
    __shared__ float w1s[144];
    __shared__ float b1s[16], b2s[32];
    __shared__ float h1p[16 * 14 * 16];   // [ic][iy][16]
    __shared__ float c2ws[32 * C2LD];     // [oc][145]: 16-way -> conflict-free
    __shared__ float h2l[1568];
    __shared__ float red[256];
    __shared__ float style[64];
    int b = blockIdx.x, tid = threadIdx.x;
    for (int i = tid; i < 196; i += 256) ((float4*)xs)[i] = ((const float4*)(img + b * 784))[i];
    for (int i = tid; i < 144; i += 256) w1s[i] = c1w[i];
    for (int i = tid; i < 4608; i += 256) c2ws[(i / 144) * C2LD + (i % 144)] = c2w[i];
    if (tid < 16) b1s[tid] = c1b[tid];
    if (tid < 32) b2s[tid] = c2b[tid];
    __syncthreads();
    // conv1: 16 oc x 14x14, stride 2 pad 1
#pragma unroll 1
    for (int o = tid; o < 3136; o += 256) {
        int oc = o / 196, pos = o % 196, oy = pos / 14, ox = pos % 14;
        float acc = b1s[oc];
        const float* wb = &w1s[oc * 9];
#pragma unroll
        for (int ky = 0; ky < 3; ky++) {
            int iy = oy * 2 - 1 + ky;
            if ((unsigned)iy < 28u) {
#pragma unroll
                for (int kx = 0; kx < 3; kx++) {
                    int ix = ox * 2 - 1 + kx;
                    if ((unsigned)ix < 28u) acc += xs[iy * 28 + ix] * wb[ky * 3 + kx];
                }
            }
        }
        h1p[oc * 224 + oy * 16 + ox] = fmaxf(acc, 0.f);
    }
    __syncthreads();
    // conv2: 32 oc x 7x7 -> h2l (LDS only)
    {
        int oc = tid & 31, oy = tid >> 5;
        if (oy < 7) {
            float a7[7];
#pragma unroll
            for (int ox = 0; ox < 7; ox++) a7[ox] = b2s[oc];
#pragma unroll 1
            for (int ic = 0; ic < 16; ic++) {
                const float* wp = &c2ws[oc * C2LD + ic * 9];
                float w[9];
#pragma unroll
                for (int t = 0; t < 9; t++) w[t] = wp[t];
#pragma unroll
                for (int ky = 0; ky < 3; ky++) {
                    int iy = oy * 2 - 1 + ky;
                    if ((unsigned)iy < 14u) {
                        const float4* rp = (const float4*)&h1p[ic * 224 + iy * 16];
                        float r[16];
#pragma unroll
                        for (int q = 0; q < 4; q++) {
                            float4 v = rp[q];
                            r[q * 4 + 0] = v.x; r[q * 4 + 1] = v.y;
                            r[q * 4 + 2] = v.z; r[q * 4 + 3] = v.w;
                        }
#pragma unroll
                        for (int ox = 0; ox < 7; ox++) {
#pragma unroll
                            for (int kx = 0; kx < 3; kx++) {
                                int ix = 2 * ox + kx - 1;
                                if (ix >= 0) a7[ox] += r[ix] * w[ky * 3 + kx];
                            }
                        }
                    }
                }
            }
            float* dst = h2l + oc * 49 + oy * 7;
#pragma unroll
            for (int ox = 0; ox < 7; ox++) dst[ox] = fmaxf(a7[ox], 0.f);
        }
    }
    __syncthreads();
    // style = tanh(h2 @ sew.T + seb), coalesced via sewTv.
    // thread (j = tid&63, p = tid>>6): 4 K-partials x 98 float4-groups.
    {
        int j = tid & 63, p = tid >> 6;
        const float4* wt = (const float4*)sewTv + j;   // + g*64 per group
        const float4* hr = (const float4*)h2l;
        float a[7] = {0.f, 0.f, 0.f, 0.f, 0.f, 0.f, 0.f};
#pragma unroll 1
        for (int gg = 0; gg < 98; gg += 7) {
#pragma unroll
            for (int u = 0; u < 7; u++) {
                int g = p * 98 + gg + u;
                float4 w = wt[g * 64];      // lane-consecutive j -> contiguous 1KB
                float4 h = hr[g];           // LDS broadcast (same addr all lanes)
                a[u] += w.x * h.x + w.y * h.y + w.z * h.z + w.w * h.w;
            }
        }
        red[p * 64 + j] = ((a[0] + a[1]) + (a[2] + a[3])) + ((a[4] + a[5]) + a[6]);
    }
    __syncthreads();
    if (tid < 64) {
        float a = seb[tid] + red[tid] + red[64 + tid] + red[128 + tid] + red[192 + tid];
        style[tid] = tanhf(a);
    }
    __syncthreads();
    // s128 = relu(style @ g1w.T + g1b) -> bf16 hi/lo split
    if (tid < 128) {
        const float4* wr = (const float4*)(g1w + tid * 64);
        const float4* sv = (const float4*)style;
        float acc = g1b[tid];
#pragma unroll
        for (int q = 0; q < 16; q++) {
            float4 w = wr[q], s = sv[q];
            acc += w.x * s.x + w.y * s.y + w.z * s.z + w.w * s.w;
        }
        float v = fmaxf(acc, 0.f);
        short hi = f2bf(v);
        Shi[b * 128 + tid] = hi;
        Slo[b * 128 + tid] = f2bf(v - bf2f(hi));
    }
}

// ---------------- g[b][t] = S[b,:128].W[t,:128] + g2b[t], bf16x3 MFMA (R6 body) ----------------
__global__ __launch_bounds__(512, 1) void gemm_k(
    const short* __restrict__ Shi, const short* __restrict__ Slo,
    const float* __restrict__ g2w, const float* __restrict__ g2b,
    float* __restrict__ g) {
    __shared__ short Bhi[128 * LDB];
    __shared__ short Blo[128 * LDB];
    int tid = threadIdx.x;
    int n0 = blockIdx.x * 128;
    {
        int r = tid >> 2, h = tid & 3;
        int t = n0 + r;
        short* dhi = Bhi + r * LDB + h * 32;
        short* dlo = Blo + r * LDB + h * 32;
        if (t < TOTAL) {
            const float4* src = (const float4*)(g2w + (long)t * 128 + h * 32);
#pragma unroll
            for (int i = 0; i < 8; i++) {
                float4 wv = src[i];
                short4v ph, pl;
                ph.x = f2bf(wv.x); ph.y = f2bf(wv.y); ph.z = f2bf(wv.z); ph.w = f2bf(wv.w);
                pl.x = f2bf(wv.x - bf2f(ph.x)); pl.y = f2bf(wv.y - bf2f(ph.y));
                pl.z = f2bf(wv.z - bf2f(ph.z)); pl.w = f2bf(wv.w - bf2f(ph.w));
                *(short4v*)(dhi + i * 4) = ph;
                *(short4v*)(dlo + i * 4) = pl;
            }
        } else {
            short4v z = {0, 0, 0, 0};
#pragma unroll
            for (int i = 0; i < 8; i++) { *(short4v*)(dhi + i * 4) = z; *(short4v*)(dlo + i * 4) = z; }
        }
    }
    __syncthreads();
    int lane = tid & 63, w = tid >> 6;
    int col = lane & 15, quad = lane >> 4;
    short8 Ah[2][4], Al[2][4];
#pragma unroll
    for (int mt = 0; mt < 2; mt++) {
        int mrow = w * 32 + mt * 16 + col;
#pragma unroll
        for (int ks = 0; ks < 4; ks++) {
            Ah[mt][ks] = *(const short8*)(Shi + mrow * 128 + ks * 32 + quad * 8);
            Al[mt][ks] = *(const short8*)(Slo + mrow * 128 + ks * 32 + quad * 8);
        }
    }
    f32x4 acc[2][8];
#pragma unroll
    for (int mt = 0; mt < 2; mt++)
#pragma unroll
        for (int nt = 0; nt < 8; nt++) acc[mt][nt] = (f32x4){0.f, 0.f, 0.f, 0.f};
#pragma unroll
    for (int nt = 0; nt < 8; nt++) {
#pragma unroll
        for (int ks = 0; ks < 4; ks++) {
            int bofs = (nt * 16 + col) * LDB + ks * 32 + quad * 8;
            short8 bh = *(const short8*)(Bhi + bofs);
            short8 bl = *(const short8*)(Blo + bofs);
#pragma unroll
            for (int mt = 0; mt < 2; mt++) {
                acc[mt][nt] = __builtin_amdgcn_mfma_f32_16x16x32_bf16(Ah[mt][ks], bh, acc[mt][nt], 0, 0, 0);
                acc[mt][nt] = __builtin_amdgcn_mfma_f32_16x16x32_bf16(Al[mt][ks], bh, acc[mt][nt], 0, 0, 0);
                acc[mt][nt] = __builtin_amdgcn_mfma_f32_16x16x32_bf16(Ah[mt][ks], bl, acc[mt][nt], 0, 0, 0);
            }
        }
    }
#pragma unroll
    for (int nt = 0; nt < 8; nt++) {
        int tcol = n0 + nt * 16 + col;
        if (tcol < TOTAL) {
            float bias = g2b[tcol];
#pragma unroll
            for (int mt = 0; mt < 2; mt++) {
                int rbase = w * 32 + mt * 16 + quad * 4;
#pragma unroll
                for (int j = 0; j < 4; j++)
                    g[(long)(rbase + j) * GSTRIDE + tcol] = acc[mt][nt][j] + bias;
            }
        }
    }
}

// ---------------- per-batch low-rank apply (512 threads/block) ----------------
__global__ __launch_bounds__(512) void apply_k(const float* __restrict__ img,
                        const float* __restrict__ g, float* __restrict__ out) {
    __shared__ float x[IN_D];
    __shared__ float red[512];
    __shared__ float v1[RANK];
    __shared__ float h1s[H1D];
    __shared__ float v2[RANK];
    int b = blockIdx.x, tid = threadIdx.x;
    const float* gb = g + (long)b * GSTRIDE;
    {
        const float4* src = (const float4*)(img + b * IN_D);
        float4* dst = (float4*)x;
        if (tid < 196) dst[tid] = src[tid];
    }
    __syncthreads();
    {
        int r = tid >> 5, p = tid & 31;
        const float4* row = (const float4*)(gb + OFF_B1F + r * IN_D);
        const float4* x4 = (const float4*)x;
        float a[7] = {0.f, 0.f, 0.f, 0.f, 0.f, 0.f, 0.f};
#pragma unroll
        for (int u = 0; u < 7; u++) {
            int i = p + u * 32;
            if (i < 196) {
                float4 w = row[i], xv = x4[i];
                a[u] += w.x * xv.x + w.y * xv.y + w.z * xv.z + w.w * xv.w;
            }
        }
        red[tid] = ((a[0] + a[1]) + (a[2] + a[3])) + ((a[4] + a[5]) + a[6]);
    }
    __syncthreads();
    if (tid < 16) {
        float s = 0.f;
#pragma unroll
        for (int p = 0; p < 32; p++) s += red[tid * 32 + p];
        v1[tid] = s;
    }
    __syncthreads();
    {
        const float4* row = (const float4*)(gb + OFF_A1 + tid * RANK);
        float acc = gb[OFF_BIAS1 + tid];
        const float4* v14 = (const float4*)v1;
#pragma unroll
        for (int q = 0; q < 4; q++) {
            float4 a = row[q], v = v14[q];
            acc += a.x * v.x + a.y * v.y + a.z * v.z + a.w * v.w;
        }
        h1s[tid] = fmaxf(acc, 0.f);
    }
    __syncthreads();
    {
        int r = tid >> 5, p = tid & 31;
        const float4* row = (const float4*)(gb + OFF_B2F + r * H1D);
        const float4* h4 = (const float4*)h1s;
        float a[4] = {0.f, 0.f, 0.f, 0.f};
#pragma unroll
        for (int u = 0; u < 4; u++) {
            int i = p + u * 32;
            float4 w = row[i], hv = h4[i];
            a[u] += w.x * hv.x + w.y * hv.y + w.z * hv.z + w.w * hv.w;
        }
        red[tid] = (a[0] + a[1]) + (a[2] + a[3]);
    }
    __syncthreads();
    if (tid < 16) {
        float s = 0.f;
#pragma unroll
        for (int p = 0; p < 32; p++) s += red[tid * 32 + p];
        v2[tid] = s;
    }
    __syncthreads();
    if (tid < OUT_D) {
        const float* row = gb + OFF_A2 + tid * RANK;
        float acc = gb[OFF_BIAS2 + tid];
#pragma unroll
        for (int r = 0; r < RANK; r++) acc += row[r] * v2[r];
        out[b * OUT_D + tid] = acc;
    }
}

extern "C" void kernel_launch(void* const* d_in, const int* in_sizes, int n_in,
                              void* d_out, int out_size, void* d_ws, size_t ws_size,
                              hipStream_t stream) {
    const float* images = (const float*)d_in[0];
    const float* c1w = (const float*)d_in[1];
    const float* c1b = (const float*)d_in[2];
    const float* c2w = (const float*)d_in[3];
    const float* c2b = (const float*)d_in[4];
    const float* sew = (const float*)d_in[5];
    const float* seb = (const float*)d_in[6];
    const float* g1w = (const float*)d_in[7];
    const float* g1b = (const float*)d_in[8];
    const float* g2w = (const float*)d_in[9];
    const float* g2b = (const float*)d_in[10];
    float* out = (float*)d_out;

    float* ws = (float*)d_ws;
    short* Shi   = (short*)ws;               // 32768 shorts
    short* Slo   = Shi + 32768;              // 32768 shorts
    float* sewTv = ws + 32768;               // 100352 floats
    float* g     = sewTv + 100352;           // 256*29616 floats (~30.3 MB)

    prep_k<<<dim3(392), dim3(256), 0, stream>>>(sew, sewTv);
    front_style_k<<<dim3(BSZ), dim3(256), 0, stream>>>(images, c1w, c1b, c2w, c2b,
                                                       sewTv, seb, g1w, g1b, Shi, Slo);
    gemm_k<<<dim3(232), dim3(512), 0, stream>>>(Shi, Slo, g2w, g2b, g);
    apply_k<<<dim3(BSZ), dim3(512), 0, stream>>>(images, g, out);
}

// Round 10
// 123.313 us; speedup vs baseline: 1.6946x; 1.0289x over previous
//
#include <hip/hip_runtime.h>
#include <math.h>

#define BSZ   256
#define RANK  16
#define IN_D  784
#define H1D   512
#define OUT_D 10
#define TOTAL 29610
#define GSTRIDE 29616   // padded g row stride (16B-aligned rows)
#define LDB 132         // LDS B row stride (shorts)
#define C2LD 145        // conv2 weight LDS row stride (odd -> conflict-free)
#define NT64 463        // ceil(TOTAL/64)

// g layout offsets (per batch row)
#define OFF_A1    0
#define OFF_B1F   8192
#define OFF_BIAS1 20736
#define OFF_A2    21248
#define OFF_B2F   21408
#define OFF_BIAS2 29600

typedef __attribute__((ext_vector_type(8))) short short8;
typedef __attribute__((ext_vector_type(4))) short short4v;
typedef __attribute__((ext_vector_type(4))) float f32x4;

__device__ __forceinline__ short f2bf(float f) {      // RNE fp32 -> bf16
    unsigned u = __float_as_uint(f);
    unsigned r = (u + 0x7fffu + ((u >> 16) & 1u)) >> 16;
    return (short)r;
}
__device__ __forceinline__ float bf2f(short s) {
    return __uint_as_float(((unsigned)(unsigned short)s) << 16);
}

// ---------------- prep: sewTv[g*256 + j*4 + c] = sew[j*1568 + g*4 + c] ----------------
__global__ __launch_bounds__(256) void prep_k(const float* __restrict__ sew,
                                              float* __restrict__ sewTv) {
    int idx = blockIdx.x * 256 + threadIdx.x;   // 392 x 256 = 100352 exactly
    int g = idx >> 8, r = idx & 255;
    int j = r >> 2, c = r & 3;
    sewTv[idx] = sew[j * 1568 + g * 4 + c];
}

// ---------------- fused conv1+conv2+style per batch (512 thr): img -> Shi/Slo ----------------
__global__ __launch_bounds__(512) void front_style_k(
    const float* __restrict__ img, const float* __restrict__ c1w, const float* __restrict__ c1b,
    const float* __restrict__ c2w, const float* __restrict__ c2b,
    const float* __restrict__ sewTv, const float* __restrict__ seb,
    const float* __restrict__ g1w, const float* __restrict__ g1b,
    short* __restrict__ Shi, short* __restrict__ Slo) {
    __shared__ float xs[784];
    __shared__ float w1s[144];
    __shared__ float b1s[16], b2s[32];
    __shared__ float h1p[16 * 14 * 16];   // [ic][iy][16]
    __shared__ float c2ws[32 * C2LD];     // [oc][145]
    __shared__ float h2l[1568];
    __shared__ float red[512];
    __shared__ float style[64];
    int b = blockIdx.x, tid = threadIdx.x;
    if (tid < 196) ((float4*)xs)[tid] = ((const float4*)(img + b * 784))[tid];
    if (tid < 144) w1s[tid] = c1w[tid];
    for (int i = tid; i < 4608; i += 512) c2ws[(i / 144) * C2LD + (i % 144)] = c2w[i];
    if (tid < 16) b1s[tid] = c1b[tid];
    if (tid < 32) b2s[tid] = c2b[tid];
    __syncthreads();
    // conv1: 16 oc x 14x14, stride 2 pad 1
#pragma unroll 1
    for (int o = tid; o < 3136; o += 512) {
        int oc = o / 196, pos = o % 196, oy = pos / 14, ox = pos % 14;
        float acc = b1s[oc];
        const float* wb = &w1s[oc * 9];
#pragma unroll
        for (int ky = 0; ky < 3; ky++) {
            int iy = oy * 2 - 1 + ky;
            if ((unsigned)iy < 28u) {
#pragma unroll
                for (int kx = 0; kx < 3; kx++) {
                    int ix = ox * 2 - 1 + kx;
                    if ((unsigned)ix < 28u) acc += xs[iy * 28 + ix] * wb[ky * 3 + kx];
                }
            }
        }
        h1p[oc * 224 + oy * 16 + ox] = fmaxf(acc, 0.f);
    }
    __syncthreads();
    // conv2: 32 oc x 7x7 -> h2l (tid<224 active)
    {
        int oc = tid & 31, oy = tid >> 5;
        if (oy < 7) {
            float a7[7];
#pragma unroll
            for (int ox = 0; ox < 7; ox++) a7[ox] = b2s[oc];
#pragma unroll 1
            for (int ic = 0; ic < 16; ic++) {
                const float* wp = &c2ws[oc * C2LD + ic * 9];
                float w[9];
#pragma unroll
                for (int t = 0; t < 9; t++) w[t] = wp[t];
#pragma unroll
                for (int ky = 0; ky < 3; ky++) {
                    int iy = oy * 2 - 1 + ky;
                    if ((unsigned)iy < 14u) {
                        const float4* rp = (const float4*)&h1p[ic * 224 + iy * 16];
                        float r[16];
#pragma unroll
                        for (int q = 0; q < 4; q++) {
                            float4 v = rp[q];
                            r[q * 4 + 0] = v.x; r[q * 4 + 1] = v.y;
                            r[q * 4 + 2] = v.z; r[q * 4 + 3] = v.w;
                        }
#pragma unroll
                        for (int ox = 0; ox < 7; ox++) {
#pragma unroll
                            for (int kx = 0; kx < 3; kx++) {
                                int ix = 2 * ox + kx - 1;
                                if (ix >= 0) a7[ox] += r[ix] * w[ky * 3 + kx];
                            }
                        }
                    }
                }
            }
            float* dst = h2l + oc * 49 + oy * 7;
#pragma unroll
            for (int ox = 0; ox < 7; ox++) dst[ox] = fmaxf(a7[ox], 0.f);
        }
    }
    __syncthreads();
    // style = tanh(h2 @ sew.T + seb), coalesced via sewTv; 8 K-partials x 49 groups
    {
        int j = tid & 63, p = tid >> 6;
        const float4* wt = (const float4*)sewTv + j;
        const float4* hr = (const float4*)h2l;
        float a[7] = {0.f, 0.f, 0.f, 0.f, 0.f, 0.f, 0.f};
#pragma unroll 1
        for (int gg = 0; gg < 49; gg += 7) {
#pragma unroll
            for (int u = 0; u < 7; u++) {
                int g = p * 49 + gg + u;
                float4 w = wt[g * 64];      // lane-consecutive j -> contiguous 1KB
                float4 h = hr[g];           // LDS broadcast
                a[u] += w.x * h.x + w.y * h.y + w.z * h.z + w.w * h.w;
            }
        }
        red[p * 64 + j] = ((a[0] + a[1]) + (a[2] + a[3])) + ((a[4] + a[5]) + a[6]);
    }
    __syncthreads();
    if (tid < 64) {
        float a = seb[tid];
#pragma unroll
        for (int p = 0; p < 8; p++) a += red[p * 64 + tid];
        style[tid] = tanhf(a);
    }
    __syncthreads();
    // s128 = relu(style @ g1w.T + g1b) -> bf16 hi/lo split
    if (tid < 128) {
        const float4* wr = (const float4*)(g1w + tid * 64);
        const float4* sv = (const float4*)style;
        float acc = g1b[tid];
#pragma unroll
        for (int q = 0; q < 16; q++) {
            float4 w = wr[q], s = sv[q];
            acc += w.x * s.x + w.y * s.y + w.z * s.z + w.w * s.w;
        }
        float v = fmaxf(acc, 0.f);
        short hi = f2bf(v);
        Shi[b * 128 + tid] = hi;
        Slo[b * 128 + tid] = f2bf(v - bf2f(hi));
    }
}

// ---------------- g = S.W^T + g2b, bf16x3 MFMA; N-tile 64 for 2 blocks/CU overlap ----------------
// grid 463, block 256 (4 waves). Wave w: m rows [64w,64w+64) = 4 m-tiles; 4 n-tiles.
// VGPR ~210 (frags 128 + acc 64) -> 2 waves/SIMD -> 2 blocks/CU resident (LDS 33.8KB).
__global__ __launch_bounds__(256, 2) void gemm_k(
    const short* __restrict__ Shi, const short* __restrict__ Slo,
    const float* __restrict__ g2w, const float* __restrict__ g2b,
    float* __restrict__ g) {
    __shared__ short Bhi[64 * LDB];
    __shared__ short Blo[64 * LDB];
    int tid = threadIdx.x;
    int n0 = blockIdx.x * 64;
    // stage + split B tile: 4 threads per row (64 rows), 32 floats each
    {
        int r = tid >> 2, h = tid & 3;
        int t = n0 + r;
        short* dhi = Bhi + r * LDB + h * 32;
        short* dlo = Blo + r * LDB + h * 32;
        if (t < TOTAL) {
            const float4* src = (const float4*)(g2w + (long)t * 128 + h * 32);
#pragma unroll
            for (int i = 0; i < 8; i++) {
                float4 wv = src[i];
                short4v ph, pl;
                ph.x = f2bf(wv.x); ph.y = f2bf(wv.y); ph.z = f2bf(wv.z); ph.w = f2bf(wv.w);
                pl.x = f2bf(wv.x - bf2f(ph.x)); pl.y = f2bf(wv.y - bf2f(ph.y));
                pl.z = f2bf(wv.z - bf2f(ph.z)); pl.w = f2bf(wv.w - bf2f(ph.w));
                *(short4v*)(dhi + i * 4) = ph;
                *(short4v*)(dlo + i * 4) = pl;
            }
        } else {
            short4v z = {0, 0, 0, 0};
#pragma unroll
            for (int i = 0; i < 8; i++) { *(short4v*)(dhi + i * 4) = z; *(short4v*)(dlo + i * 4) = z; }
        }
    }
    __syncthreads();
    int lane = tid & 63, w = tid >> 6;
    int col = lane & 15, quad = lane >> 4;
    // A fragments for 4 m-tiles: A[m = lane&15][k = quad*8+j]
    short8 Ah[4][4], Al[4][4];
#pragma unroll
    for (int mt = 0; mt < 4; mt++) {
        int mrow = w * 64 + mt * 16 + col;
#pragma unroll
        for (int ks = 0; ks < 4; ks++) {
            Ah[mt][ks] = *(const short8*)(Shi + mrow * 128 + ks * 32 + quad * 8);
            Al[mt][ks] = *(const short8*)(Slo + mrow * 128 + ks * 32 + quad * 8);
        }
    }
    f32x4 acc[4][4];
#pragma unroll
    for (int mt = 0; mt < 4; mt++)
#pragma unroll
        for (int nt = 0; nt < 4; nt++) acc[mt][nt] = (f32x4){0.f, 0.f, 0.f, 0.f};
#pragma unroll
    for (int nt = 0; nt < 4; nt++) {
#pragma unroll
        for (int ks = 0; ks < 4; ks++) {
            int bofs = (nt * 16 + col) * LDB + ks * 32 + quad * 8;
            short8 bh = *(const short8*)(Bhi + bofs);
            short8 bl = *(const short8*)(Blo + bofs);
#pragma unroll
            for (int mt = 0; mt < 4; mt++) {
                acc[mt][nt] = __builtin_amdgcn_mfma_f32_16x16x32_bf16(Ah[mt][ks], bh, acc[mt][nt], 0, 0, 0);
                acc[mt][nt] = __builtin_amdgcn_mfma_f32_16x16x32_bf16(Al[mt][ks], bh, acc[mt][nt], 0, 0, 0);
                acc[mt][nt] = __builtin_amdgcn_mfma_f32_16x16x32_bf16(Ah[mt][ks], bl, acc[mt][nt], 0, 0, 0);
            }
        }
    }
    // epilogue: C col = lane&15 (t), row = quad*4 + j (batch)
#pragma unroll
    for (int nt = 0; nt < 4; nt++) {
        int tcol = n0 + nt * 16 + col;
        if (tcol < TOTAL) {
            float bias = g2b[tcol];
#pragma unroll
            for (int mt = 0; mt < 4; mt++) {
                int rbase = w * 64 + mt * 16 + quad * 4;
#pragma unroll
                for (int j = 0; j < 4; j++)
                    g[(long)(rbase + j) * GSTRIDE + tcol] = acc[mt][nt][j] + bias;
            }
        }
    }
}

// ---------------- per-batch low-rank apply (512 threads/block) ----------------
__global__ __launch_bounds__(512) void apply_k(const float* __restrict__ img,
                        const float* __restrict__ g, float* __restrict__ out) {
    __shared__ float x[IN_D];
    __shared__ float red[512];
    __shared__ float v1[RANK];
    __shared__ float h1s[H1D];
    __shared__ float v2[RANK];
    int b = blockIdx.x, tid = threadIdx.x;
    const float* gb = g + (long)b * GSTRIDE;
    {
        const float4* src = (const float4*)(img + b * IN_D);
        float4* dst = (float4*)x;
        if (tid < 196) dst[tid] = src[tid];
    }
    __syncthreads();
    {
        int r = tid >> 5, p = tid & 31;
        const float4* row = (const float4*)(gb + OFF_B1F + r * IN_D);
        const float4* x4 = (const float4*)x;
        float a[7] = {0.f, 0.f, 0.f, 0.f, 0.f, 0.f, 0.f};
#pragma unroll
        for (int u = 0; u < 7; u++) {
            int i = p + u * 32;
            if (i < 196) {
                float4 w = row[i], xv = x4[i];
                a[u] += w.x * xv.x + w.y * xv.y + w.z * xv.z + w.w * xv.w;
            }
        }
        red[tid] = ((a[0] + a[1]) + (a[2] + a[3])) + ((a[4] + a[5]) + a[6]);
    }
    __syncthreads();
    if (tid < 16) {
        float s = 0.f;
#pragma unroll
        for (int p = 0; p < 32; p++) s += red[tid * 32 + p];
        v1[tid] = s;
    }
    __syncthreads();
    {
        const float4* row = (const float4*)(gb + OFF_A1 + tid * RANK);
        float acc = gb[OFF_BIAS1 + tid];
        const float4* v14 = (const float4*)v1;
#pragma unroll
        for (int q = 0; q < 4; q++) {
            float4 a = row[q], v = v14[q];
            acc += a.x * v.x + a.y * v.y + a.z * v.z + a.w * v.w;
        }
        h1s[tid] = fmaxf(acc, 0.f);
    }
    __syncthreads();
    {
        int r = tid >> 5, p = tid & 31;
        const float4* row = (const float4*)(gb + OFF_B2F + r * H1D);
        const float4* h4 = (const float4*)h1s;
        float a[4] = {0.f, 0.f, 0.f, 0.f};
#pragma unroll
        for (int u = 0; u < 4; u++) {
            int i = p + u * 32;
            float4 w = row[i], hv = h4[i];
            a[u] += w.x * hv.x + w.y * hv.y + w.z * hv.z + w.w * hv.w;
        }
        red[tid] = (a[0] + a[1]) + (a[2] + a[3]);
    }
    __syncthreads();
    if (tid < 16) {
        float s = 0.f;
#pragma unroll
        for (int p = 0; p < 32; p++) s += red[tid * 32 + p];
        v2[tid] = s;
    }
    __syncthreads();
    if (tid < OUT_D) {
        const float* row = gb + OFF_A2 + tid * RANK;
        float acc = gb[OFF_BIAS2 + tid];
#pragma unroll
        for (int r = 0; r < RANK; r++) acc += row[r] * v2[r];
        out[b * OUT_D + tid] = acc;
    }
}

extern "C" void kernel_launch(void* const* d_in, const int* in_sizes, int n_in,
                              void* d_out, int out_size, void* d_ws, size_t ws_size,
                              hipStream_t stream) {
    const float* images = (const float*)d_in[0];
    const float* c1w = (const float*)d_in[1];
    const float* c1b = (const float*)d_in[2];
    const float* c2w = (const float*)d_in[3];
    const float* c2b = (const float*)d_in[4];
    const float* sew = (const float*)d_in[5];
    const float* seb = (const float*)d_in[6];
    const float* g1w = (const float*)d_in[7];
    const float* g1b = (const float*)d_in[8];
    const float* g2w = (const float*)d_in[9];
    const float* g2b = (const float*)d_in[10];
    float* out = (float*)d_out;

    float* ws = (float*)d_ws;
    short* Shi   = (short*)ws;               // 32768 shorts
    short* Slo   = Shi + 32768;              // 32768 shorts
    float* sewTv = ws + 32768;               // 100352 floats
    float* g     = sewTv + 100352;           // 256*29616 floats (~30.3 MB)

    prep_k<<<dim3(392), dim3(256), 0, stream>>>(sew, sewTv);
    front_style_k<<<dim3(BSZ), dim3(512), 0, stream>>>(images, c1w, c1b, c2w, c2b,
                                                       sewTv, seb, g1w, g1b, Shi, Slo);
    gemm_k<<<dim3(NT64), dim3(256), 0, stream>>>(Shi, Slo, g2w, g2b, g);
    apply_k<<<dim3(BSZ), dim3(512), 0, stream>>>(images, g, out);
}